// Round 4
// baseline (484.464 us; speedup 1.0000x reference)
//
#include <hip/hip_runtime.h>
#include <hip/hip_bf16.h>
#include <math.h>

#define BB 8
#define TT 1024
#define DD 256
#define HH 8
#define BT 8192   // B*T

typedef __attribute__((ext_vector_type(4))) float f32x4;
typedef __attribute__((ext_vector_type(16))) float f32x16;
typedef __attribute__((ext_vector_type(8))) short short8;
typedef __attribute__((ext_vector_type(4))) short short4v;
typedef __attribute__((ext_vector_type(8))) __bf16 bf16x8;

__device__ inline float bf2f(short s) {
  unsigned int u = ((unsigned int)(unsigned short)s) << 16;
  return __builtin_bit_cast(float, u);
}
__device__ inline short f2bf(float f) {
  unsigned int u = __builtin_bit_cast(unsigned int, f);
  unsigned int lsb = (u >> 16) & 1u;
  u += 0x7fffu + lsb;
  return (short)(u >> 16);
}
__device__ inline unsigned int cvtpk(float lo, float hi) {
  unsigned int r;
  asm("v_cvt_pk_bf16_f32 %0, %1, %2" : "=v"(r) : "v"(lo), "v"(hi));
  return r;
}

__device__ inline f32x4 mfma16(short8 a, short8 b, f32x4 c) {
  return __builtin_amdgcn_mfma_f32_16x16x32_bf16(
      __builtin_bit_cast(bf16x8, a), __builtin_bit_cast(bf16x8, b), c, 0, 0, 0);
}
__device__ inline f32x16 mfma32(short8 a, short8 b, f32x16 c) {
  return __builtin_amdgcn_mfma_f32_32x32x16_bf16(
      __builtin_bit_cast(bf16x8, a), __builtin_bit_cast(bf16x8, b), c, 0, 0, 0);
}

__device__ inline void gload_lds16(void* lds, const void* g) {
  __builtin_amdgcn_global_load_lds(
      (const __attribute__((address_space(1))) unsigned int*)g,
      (__attribute__((address_space(3))) unsigned int*)lds, 16, 0, 0);
}

// ---------------- weight fp32 -> bf16 convert (vectorized) ----------------
__global__ void cvt_kernel(const float4* __restrict__ src, short4v* __restrict__ dst, int n4) {
  int i = blockIdx.x * 256 + threadIdx.x;
  if (i < n4) {
    float4 v = src[i];
    short4v o;
    o[0] = f2bf(v.x); o[1] = f2bf(v.y); o[2] = f2bf(v.z); o[3] = f2bf(v.w);
    dst[i] = o;
  }
}

// ---------------- LayerNorm (optionally double LN) ----------------
__global__ __launch_bounds__(256) void ln_kernel(
    const float* __restrict__ Xin,
    const float* __restrict__ g1, const float* __restrict__ b1,
    const float* __restrict__ g2, const float* __restrict__ b2,
    short* __restrict__ out, int dbl)
{
  const int row = blockIdx.x * 4 + (threadIdx.x >> 6);
  const int lane = threadIdx.x & 63;
  const float4 v = *(const float4*)(Xin + (size_t)row * 256 + lane * 4);
  float y[4] = {v.x, v.y, v.z, v.w};

  float s = y[0] + y[1] + y[2] + y[3];
  #pragma unroll
  for (int m = 32; m >= 1; m >>= 1) s += __shfl_xor(s, m, 64);
  float mean = s * (1.0f / 256.0f);
  float sq = 0.f;
  #pragma unroll
  for (int i = 0; i < 4; ++i) { y[i] -= mean; sq += y[i] * y[i]; }
  #pragma unroll
  for (int m = 32; m >= 1; m >>= 1) sq += __shfl_xor(sq, m, 64);
  float rs = rsqrtf(sq * (1.0f / 256.0f) + 1e-6f);
  #pragma unroll
  for (int i = 0; i < 4; ++i) y[i] = y[i] * rs * g1[lane * 4 + i] + b1[lane * 4 + i];

  if (dbl) {
    float s2 = y[0] + y[1] + y[2] + y[3];
    #pragma unroll
    for (int m = 32; m >= 1; m >>= 1) s2 += __shfl_xor(s2, m, 64);
    float m2 = s2 * (1.0f / 256.0f);
    float sq2 = 0.f;
    #pragma unroll
    for (int i = 0; i < 4; ++i) { y[i] -= m2; sq2 += y[i] * y[i]; }
    #pragma unroll
    for (int m = 32; m >= 1; m >>= 1) sq2 += __shfl_xor(sq2, m, 64);
    float rs2 = rsqrtf(sq2 * (1.0f / 256.0f) + 1e-6f);
    #pragma unroll
    for (int i = 0; i < 4; ++i) y[i] = y[i] * rs2 * g2[lane * 4 + i] + b2[lane * 4 + i];
  }
  #pragma unroll
  for (int i = 0; i < 4; ++i) out[(size_t)row * 256 + lane * 4 + i] = f2bf(y[i]);
}

// ---------------- Q/K l2norm prepass (in place on qkv_bf) ----------------
// Q lanes (0..31) additionally scaled by SCALE*log2(e) so attention scores land
// directly in the exp2 domain.
__global__ __launch_bounds__(256) void qknorm_kernel(short* __restrict__ qkv) {
  const int row = blockIdx.x * 4 + (threadIdx.x >> 6);
  const int lane = threadIdx.x & 63;
  short* p = qkv + (size_t)row * 768 + lane * 8;
  short8 v = *(short8*)p;
  float f[8]; float ss = 0.f;
  #pragma unroll
  for (int j = 0; j < 8; ++j) { f[j] = bf2f(v[j]); ss += f[j] * f[j]; }
  ss += __shfl_xor(ss, 1, 64);
  ss += __shfl_xor(ss, 2, 64);
  float inv = 1.0f / fmaxf(sqrtf(ss), 1e-8f);
  const float C2 = 0.25503489702966368f;   // (1/sqrt(32)) * log2(e)
  float sc = (lane < 32) ? inv * C2 : inv;
  short8 o;
  #pragma unroll
  for (int j = 0; j < 8; ++j) o[j] = f2bf(f[j] * sc);
  *(short8*)p = o;
}

// ---------------- GEMM: C[M,N] = A[M,K] @ Bw[N,K]^T (+epilogue) ----------------
template<int BN, int EPI>
__global__ __launch_bounds__(256) void gemm_bt(
    const short* __restrict__ A, const short* __restrict__ Bw,
    const float* __restrict__ bias, float* __restrict__ X,
    short* __restrict__ Obf, const float* __restrict__ scale_p,
    int M, int N, int K)
{
  constexpr int MI = (BN == 128) ? 4 : 2;
  __shared__ __align__(16) short A_s[128 * 64];
  __shared__ __align__(16) short B_s[BN * 64];
  const int tid = threadIdx.x;
  const int lane = tid & 63;
  const int w = tid >> 6;
  const int lo4 = lane & 15, hi2 = lane >> 4;
  int wm, wn0;
  if (BN == 128) { wm = (w >> 1) * 64; wn0 = (w & 1) * 64; }
  else           { wm = w * 32;        wn0 = 0; }
  // bijective XCD swizzle (all grids divisible by 8)
  const int bid = blockIdx.x + blockIdx.y * gridDim.x;
  const int nwg = gridDim.x * gridDim.y;
  const int wg = (bid & 7) * (nwg >> 3) + (bid >> 3);
  const int tM = (wg / gridDim.x) * 128, tN = (wg % gridDim.x) * BN;

  f32x4 acc[MI][4];
  #pragma unroll
  for (int i = 0; i < MI; ++i)
    #pragma unroll
    for (int j = 0; j < 4; ++j) acc[i][j] = (f32x4){0.f, 0.f, 0.f, 0.f};

  const int swz = (lo4 & 7) << 3;

  for (int k0 = 0; k0 < K; k0 += 64) {
    #pragma unroll
    for (int ri = 0; ri < 4; ++ri) {
      int o = ri * 2048 + tid * 8;
      int row = o >> 6;
      int col = (o & 63) ^ ((row & 7) << 3);
      gload_lds16(&A_s[ri * 2048 + w * 512], A + (size_t)(tM + row) * K + k0 + col);
    }
    #pragma unroll
    for (int ri = 0; ri < BN / 32; ++ri) {
      int o = ri * 2048 + tid * 8;
      int row = o >> 6;
      int col = (o & 63) ^ ((row & 7) << 3);
      gload_lds16(&B_s[ri * 2048 + w * 512], Bw + (size_t)(tN + row) * K + k0 + col);
    }
    __syncthreads();
    #pragma unroll
    for (int kc = 0; kc < 2; ++kc) {
      short8 af[MI], bfr[4];
      #pragma unroll
      for (int i = 0; i < MI; ++i)
        af[i] = *(const short8*)&A_s[(wm + i * 16 + lo4) * 64 + ((kc * 32 + hi2 * 8) ^ swz)];
      #pragma unroll
      for (int j = 0; j < 4; ++j)
        bfr[j] = *(const short8*)&B_s[(wn0 + j * 16 + lo4) * 64 + ((kc * 32 + hi2 * 8) ^ swz)];
      #pragma unroll
      for (int i = 0; i < MI; ++i)
        #pragma unroll
        for (int j = 0; j < 4; ++j)
          acc[i][j] = mfma16(af[i], bfr[j], acc[i][j]);
    }
    __syncthreads();
  }

  float ts = 0.f;
  if (EPI == 1 || EPI == 3) ts = tanhf(scale_p[0]);

  #pragma unroll
  for (int i = 0; i < MI; ++i) {
    #pragma unroll
    for (int j = 0; j < 4; ++j) {
      #pragma unroll
      for (int r = 0; r < 4; ++r) {
        int row = tM + wm + i * 16 + hi2 * 4 + r;
        int col = tN + wn0 + j * 16 + lo4;
        float v = acc[i][j][r] + bias[col];
        size_t idx = (size_t)row * N + col;
        if (EPI == 0) {
          Obf[idx] = f2bf(v);
        } else if (EPI == 1) {
          X[idx] += ts * (v * 0.5f);
        } else if (EPI == 2) {
          float gl = 0.5f * v * (1.0f + erff(v * 0.70710678118f));
          Obf[idx] = f2bf(gl);
        } else {
          float o = X[idx] + ts * v;
          o = fminf(100.f, fmaxf(-100.f, o));
          X[idx] = o;
        }
      }
    }
  }
}

// ---------------- 64x64-tile GEMM for the N=256 layers ----------------
template<int EPI>
__global__ __launch_bounds__(256) void gemm64(
    const short* __restrict__ A, const short* __restrict__ Bw,
    const float* __restrict__ bias, float* __restrict__ X,
    const float* __restrict__ scale_p, int M, int N, int K)
{
  __shared__ __align__(16) short A_s[64 * 64];
  __shared__ __align__(16) short B_s[64 * 64];
  const int tid = threadIdx.x;
  const int lane = tid & 63;
  const int w = tid >> 6;
  const int lo4 = lane & 15, hi2 = lane >> 4;
  const int wm = (w >> 1) * 32, wn0 = (w & 1) * 32;
  const int bid = blockIdx.x + blockIdx.y * gridDim.x;
  const int nwg = gridDim.x * gridDim.y;
  const int wg = (bid & 7) * (nwg >> 3) + (bid >> 3);
  const int tM = (wg / gridDim.x) * 64, tN = (wg % gridDim.x) * 64;

  f32x4 acc[2][2];
  #pragma unroll
  for (int i = 0; i < 2; ++i)
    #pragma unroll
    for (int j = 0; j < 2; ++j) acc[i][j] = (f32x4){0.f, 0.f, 0.f, 0.f};

  const int swz = (lo4 & 7) << 3;

  for (int k0 = 0; k0 < K; k0 += 64) {
    #pragma unroll
    for (int ri = 0; ri < 2; ++ri) {
      int o = ri * 2048 + tid * 8;
      int row = o >> 6;
      int col = (o & 63) ^ ((row & 7) << 3);
      gload_lds16(&A_s[ri * 2048 + w * 512], A + (size_t)(tM + row) * K + k0 + col);
      gload_lds16(&B_s[ri * 2048 + w * 512], Bw + (size_t)(tN + row) * K + k0 + col);
    }
    __syncthreads();
    #pragma unroll
    for (int kc = 0; kc < 2; ++kc) {
      short8 af[2], bfr[2];
      #pragma unroll
      for (int i = 0; i < 2; ++i)
        af[i] = *(const short8*)&A_s[(wm + i * 16 + lo4) * 64 + ((kc * 32 + hi2 * 8) ^ swz)];
      #pragma unroll
      for (int j = 0; j < 2; ++j)
        bfr[j] = *(const short8*)&B_s[(wn0 + j * 16 + lo4) * 64 + ((kc * 32 + hi2 * 8) ^ swz)];
      #pragma unroll
      for (int i = 0; i < 2; ++i)
        #pragma unroll
        for (int j = 0; j < 2; ++j)
          acc[i][j] = mfma16(af[i], bfr[j], acc[i][j]);
    }
    __syncthreads();
  }

  float ts = tanhf(scale_p[0]);

  #pragma unroll
  for (int i = 0; i < 2; ++i) {
    #pragma unroll
    for (int j = 0; j < 2; ++j) {
      #pragma unroll
      for (int r = 0; r < 4; ++r) {
        int row = tM + wm + i * 16 + hi2 * 4 + r;
        int col = tN + wn0 + j * 16 + lo4;
        float v = acc[i][j][r] + bias[col];
        size_t idx = (size_t)row * N + col;
        if (EPI == 1) {
          X[idx] += ts * (v * 0.5f);
        } else {
          float o = X[idx] + ts * v;
          o = fminf(100.f, fmaxf(-100.f, o));
          X[idx] = o;
        }
      }
    }
  }
}

// ---------------- fused causal attention, 2-wave blocks, 64-query tiles ------
// Grid (16,64), block 128. li -> (b = li&7 [XCD-local KV], h, qt descending).
// Q pre-scaled by SCALE*log2e -> softmax numerator = exp2(med3(S,-C,C)).
#define KG_BODY(KG, PKO, MASKED)                                                   \
  {                                                                                \
    const int krow = ((KG) * 32 + lo5) * 32;                                       \
    short8 kf0 = *(const short8*)&K_s[cur][krow + ((hi1 ^ (lo5 & 3)) * 8)];        \
    short8 kf1 = *(const short8*)&K_s[cur][krow + (((2 + hi1) ^ (lo5 & 3)) * 8)];  \
    f32x16 z = (f32x16)0.0f;                                                       \
    z = mfma32(kf0, qb[0], z);                                                     \
    z = mfma32(kf1, qb[1], z);                                                     \
    float pr[16];                                                                  \
    _Pragma("unroll")                                                              \
    for (int r = 0; r < 16; ++r) {                                                 \
      float sv = __builtin_amdgcn_fmed3f(z[r], -14.4269504f, 14.4269504f);         \
      float pe;                                                                    \
      asm("v_exp_f32 %0, %1" : "=v"(pe) : "v"(sv));                                \
      const int keyrel = (r & 3) + 8 * (r >> 2) + 4 * hi1;                         \
      if (MASKED) pe = (keyrel > lo5) ? 0.f : pe;                                  \
      if (pm) pe = ((pm >> ((KG) * 32 + keyrel)) & 1ull) ? 0.f : pe;               \
      pr[r] = pe;                                                                  \
      rsum += pe;                                                                  \
    }                                                                              \
    _Pragma("unroll")                                                              \
    for (int i = 0; i < 8; ++i) PKO[i] = cvtpk(pr[2 * i], pr[2 * i + 1]);          \
  }

#define PV_CHUNK(K2, PKO)                                                          \
  {                                                                                \
    const int half = (K2) & 1;                                                     \
    unsigned int keep0 = hi1 ? PKO[4 * half + 2] : PKO[4 * half + 0];              \
    unsigned int keep1 = hi1 ? PKO[4 * half + 3] : PKO[4 * half + 1];              \
    unsigned int send0 = hi1 ? PKO[4 * half + 0] : PKO[4 * half + 2];              \
    unsigned int send1 = hi1 ? PKO[4 * half + 1] : PKO[4 * half + 3];              \
    unsigned int r0 = (unsigned int)__shfl_xor((int)send0, 32, 64);                \
    unsigned int r1 = (unsigned int)__shfl_xor((int)send1, 32, 64);                \
    union { unsigned int u[4]; short8 s; } fa;                                     \
    fa.u[0] = hi1 ? r0 : keep0;                                                    \
    fa.u[1] = hi1 ? r1 : keep1;                                                    \
    fa.u[2] = hi1 ? keep0 : r0;                                                    \
    fa.u[3] = hi1 ? keep1 : r1;                                                    \
    const int g = (((K2) * 2 + hi1) ^ (lo5 & 7) ^ (lo5 >> 3)) & 7;                 \
    short8 vb = *(const short8*)&V_s[cur][lo5 * 64 + g * 8];                       \
    if ((K2) & 1) oaccB = mfma32(fa.s, vb, oaccB);                                 \
    else          oaccA = mfma32(fa.s, vb, oaccA);                                 \
  }

__global__ __launch_bounds__(128, 4) void attn_kernel(
    const short* __restrict__ qkv, const unsigned char* __restrict__ pad,
    short* __restrict__ ao)
{
  __shared__ __align__(16) short K_s[2][2048];
  __shared__ __align__(16) short V_s[2][2048];
  __shared__ __align__(8) unsigned char Pm_s[128];

  const int tid = threadIdx.x, lane = tid & 63, w = tid >> 6;
  const int lo5 = lane & 31, hi1 = lane >> 5;
  const int li = blockIdx.x + blockIdx.y * 16;
  const int slot = li >> 3;
  const int qt = 15 - (slot >> 3);     // longest blocks dispatched first
  const int b = li & 7;                // XCD-local batch -> KV stays in one L2
  const int h = slot & 7;
  const size_t rowbase = (size_t)b * TT;
  const int qrow = qt * 64 + w * 32 + lo5;
  const int nt = qt + 1;

  {
    unsigned long long c = ((const unsigned long long*)(pad + rowbase))[tid];
    unsigned int by = 0;
    #pragma unroll
    for (int j = 0; j < 8; ++j) by |= (unsigned int)((c >> (8 * j)) & 1ull) << j;
    Pm_s[tid] = (unsigned char)by;
  }

  short8 qb[2];
  #pragma unroll
  for (int c2 = 0; c2 < 2; ++c2)
    qb[c2] = *(const short8*)(qkv + (rowbase + qrow) * 768 + h * 32 + c2 * 16 + hi1 * 8);

  // K staging: 2 rounds/wave, linear LDS dest, source pre-swizzled
  const int kkey0 = w * 16 + (lane >> 2);
  const int kcol = ((lane & 3) ^ (kkey0 & 3)) * 8;
  const short* Ksrc0 = qkv + (rowbase + kkey0) * 768 + 256 + h * 32 + kcol;
  const short* Ksrc1 = Ksrc0 + (size_t)32 * 768;
  // V staging: 2 rounds, reg-staged, transposed+swizzled LDS store
  const int vkey0 = tid >> 2;
  const int vdg = tid & 3;
  const short* Vsrc0 = qkv + (rowbase + vkey0) * 768 + 512 + h * 32 + vdg * 8;
  const short* Vsrc1 = Vsrc0 + (size_t)32 * 768;
  int vwo[8];
  #pragma unroll
  for (int j = 0; j < 8; ++j)
    vwo[j] = (vdg * 8 + j) * 64 + ((((vkey0 >> 3) ^ j ^ vdg) & 7) * 8) + (vkey0 & 7);

  gload_lds16(&K_s[0][w * 512], Ksrc0);
  gload_lds16(&K_s[0][1024 + w * 512], Ksrc1);
  {
    short8 v0 = *(const short8*)Vsrc0;
    short8 v1 = *(const short8*)Vsrc1;
    #pragma unroll
    for (int j = 0; j < 8; ++j) V_s[0][vwo[j]] = v0[j];
    #pragma unroll
    for (int j = 0; j < 8; ++j) V_s[0][vwo[j] ^ 32] = v1[j];
  }
  __syncthreads();

  f32x16 oaccA = (f32x16)0.0f;
  f32x16 oaccB = (f32x16)0.0f;
  float rsum = 0.f;

  for (int t = 0; t < nt; ++t) {
    const int cur = t & 1, nxt = cur ^ 1;
    const bool pre = (t + 1 < nt);
    short8 v0n, v1n;
    if (pre) {
      const size_t adv = (size_t)(t + 1) * 64 * 768;
      gload_lds16(&K_s[nxt][w * 512], Ksrc0 + adv);
      gload_lds16(&K_s[nxt][1024 + w * 512], Ksrc1 + adv);
      v0n = *(const short8*)(Vsrc0 + adv);
      v1n = *(const short8*)(Vsrc1 + adv);
    }
    const bool fin = (t + 1 == nt);
    const unsigned long long pm = ((const unsigned long long*)Pm_s)[t];

    unsigned int pk0[8], pk1[8];
    const bool m0 = fin && (w == 0);
    KG_BODY(0, pk0, m0)
    PV_CHUNK(0, pk0)
    PV_CHUNK(1, pk0)
    if (!fin || w == 1) {
      KG_BODY(1, pk1, fin)
      PV_CHUNK(2, pk1)
      PV_CHUNK(3, pk1)
    }

    if (pre) {
      #pragma unroll
      for (int j = 0; j < 8; ++j) V_s[nxt][vwo[j]] = v0n[j];
      #pragma unroll
      for (int j = 0; j < 8; ++j) V_s[nxt][vwo[j] ^ 32] = v1n[j];
    }
    __syncthreads();
  }

  rsum += __shfl_xor(rsum, 32, 64);
  float rinv = 1.0f / fmaxf(rsum, 1e-30f);
  #pragma unroll
  for (int r = 0; r < 16; ++r) {
    int ql = (r & 3) + 8 * (r >> 2) + 4 * hi1;
    float riv = __shfl(rinv, ql, 64);
    int qg = qt * 64 + w * 32 + ql;
    ao[(rowbase + qg) * 256 + h * 32 + lo5] = f2bf((oaccA[r] + oaccB[r]) * riv);
  }
}

extern "C" void kernel_launch(void* const* d_in, const int* in_sizes, int n_in,
                              void* d_out, int out_size, void* d_ws, size_t ws_size,
                              hipStream_t stream) {
  const float* x_in  = (const float*)d_in[0];
  const unsigned char* pad = (const unsigned char*)d_in[1];
  const float* ln1_g = (const float*)d_in[2];
  const float* ln1_b = (const float*)d_in[3];
  const float* qn_g  = (const float*)d_in[4];
  const float* qn_b  = (const float*)d_in[5];
  const float* Wqkv  = (const float*)d_in[6];
  const float* bqkv  = (const float*)d_in[7];
  const float* Wo    = (const float*)d_in[8];
  const float* bo    = (const float*)d_in[9];
  const float* ln2_g = (const float*)d_in[10];
  const float* ln2_b = (const float*)d_in[11];
  const float* W1    = (const float*)d_in[12];
  const float* b1    = (const float*)d_in[13];
  const float* W2    = (const float*)d_in[14];
  const float* b2    = (const float*)d_in[15];
  const float* alpha = (const float*)d_in[16];
  const float* beta  = (const float*)d_in[17];

  char* ws = (char*)d_ws;
  size_t off = 0;
  short* wqkv_bf = (short*)(ws + off); off += (size_t)4 * 768 * 256 * 2;
  short* wo_bf   = (short*)(ws + off); off += (size_t)4 * 256 * 256 * 2;
  short* w1_bf   = (short*)(ws + off); off += (size_t)4 * 1024 * 256 * 2;
  short* w2_bf   = (short*)(ws + off); off += (size_t)4 * 256 * 1024 * 2;
  short* h_bf    = (short*)(ws + off); off += (size_t)BT * 256 * 2;
  short* qkv_bf  = (short*)(ws + off); off += (size_t)BT * 768 * 2;
  short* ao_bf   = (short*)(ws + off); off += (size_t)BT * 256 * 2;
  short* g_bf    = (short*)(ws + off); off += (size_t)BT * 1024 * 2;

  float* X = (float*)d_out;

  hipMemcpyAsync(d_out, x_in, (size_t)BT * DD * 4, hipMemcpyDeviceToDevice, stream);
  cvt_kernel<<<768,  256, 0, stream>>>((const float4*)Wqkv, (short4v*)wqkv_bf, 4 * 768 * 256 / 4);
  cvt_kernel<<<256,  256, 0, stream>>>((const float4*)Wo,   (short4v*)wo_bf,   4 * 256 * 256 / 4);
  cvt_kernel<<<1024, 256, 0, stream>>>((const float4*)W1,   (short4v*)w1_bf,   4 * 1024 * 256 / 4);
  cvt_kernel<<<1024, 256, 0, stream>>>((const float4*)W2,   (short4v*)w2_bf,   4 * 256 * 1024 / 4);

  for (int l = 0; l < 4; ++l) {
    ln_kernel<<<2048, 256, 0, stream>>>(X, ln1_g + l * 256, ln1_b + l * 256,
                                        qn_g + l * 256, qn_b + l * 256, h_bf, 1);
    gemm_bt<128, 0><<<dim3(6, 64), 256, 0, stream>>>(h_bf, wqkv_bf + (size_t)l * 768 * 256,
                                                     bqkv + l * 768, nullptr, qkv_bf, nullptr,
                                                     8192, 768, 256);
    qknorm_kernel<<<2048, 256, 0, stream>>>(qkv_bf);
    attn_kernel<<<dim3(16, 64), 128, 0, stream>>>(qkv_bf, pad, ao_bf);
    gemm64<1><<<dim3(4, 128), 256, 0, stream>>>(ao_bf, wo_bf + (size_t)l * 256 * 256,
                                                bo + l * 256, X, alpha + l,
                                                8192, 256, 256);
    ln_kernel<<<2048, 256, 0, stream>>>(X, ln2_g + l * 256, ln2_b + l * 256,
                                        nullptr, nullptr, h_bf, 0);
    gemm_bt<128, 2><<<dim3(8, 64), 256, 0, stream>>>(h_bf, w1_bf + (size_t)l * 1024 * 256,
                                                     b1 + l * 1024, nullptr, g_bf, nullptr,
                                                     8192, 1024, 256);
    gemm64<3><<<dim3(4, 128), 256, 0, stream>>>(g_bf, w2_bf + (size_t)l * 256 * 1024,
                                                b2 + l * 256, X, beta + l,
                                                8192, 256, 1024);
  }
}

// Round 5
// 376.052 us; speedup vs baseline: 1.2883x; 1.2883x over previous
//
#include <hip/hip_runtime.h>
#include <hip/hip_bf16.h>
#include <math.h>

#define BB 8
#define TT 1024
#define DD 256
#define HH 8
#define BT 8192   // B*T

typedef __attribute__((ext_vector_type(4))) float f32x4;
typedef __attribute__((ext_vector_type(16))) float f32x16;
typedef __attribute__((ext_vector_type(8))) short short8;
typedef __attribute__((ext_vector_type(4))) short short4v;
typedef __attribute__((ext_vector_type(8))) __bf16 bf16x8;

__device__ inline float bf2f(short s) {
  unsigned int u = ((unsigned int)(unsigned short)s) << 16;
  return __builtin_bit_cast(float, u);
}
__device__ inline short f2bf(float f) {
  unsigned int u = __builtin_bit_cast(unsigned int, f);
  unsigned int lsb = (u >> 16) & 1u;
  u += 0x7fffu + lsb;
  return (short)(u >> 16);
}
__device__ inline unsigned int cvtpk(float lo, float hi) {
  unsigned int r;
  asm("v_cvt_pk_bf16_f32 %0, %1, %2" : "=v"(r) : "v"(lo), "v"(hi));
  return r;
}

__device__ inline f32x4 mfma16(short8 a, short8 b, f32x4 c) {
  return __builtin_amdgcn_mfma_f32_16x16x32_bf16(
      __builtin_bit_cast(bf16x8, a), __builtin_bit_cast(bf16x8, b), c, 0, 0, 0);
}
__device__ inline f32x16 mfma32(short8 a, short8 b, f32x16 c) {
  return __builtin_amdgcn_mfma_f32_32x32x16_bf16(
      __builtin_bit_cast(bf16x8, a), __builtin_bit_cast(bf16x8, b), c, 0, 0, 0);
}

__device__ inline void gload_lds16(void* lds, const void* g) {
  __builtin_amdgcn_global_load_lds(
      (const __attribute__((address_space(1))) unsigned int*)g,
      (__attribute__((address_space(3))) unsigned int*)lds, 16, 0, 0);
}

// ---------------- weight fp32 -> bf16 convert (vectorized) ----------------
__global__ void cvt_kernel(const float4* __restrict__ src, short4v* __restrict__ dst, int n4) {
  int i = blockIdx.x * 256 + threadIdx.x;
  if (i < n4) {
    float4 v = src[i];
    short4v o;
    o[0] = f2bf(v.x); o[1] = f2bf(v.y); o[2] = f2bf(v.z); o[3] = f2bf(v.w);
    dst[i] = o;
  }
}

// ---------------- LayerNorm (optionally double LN) ----------------
__global__ __launch_bounds__(256) void ln_kernel(
    const float* __restrict__ Xin,
    const float* __restrict__ g1, const float* __restrict__ b1,
    const float* __restrict__ g2, const float* __restrict__ b2,
    short* __restrict__ out, int dbl)
{
  const int row = blockIdx.x * 4 + (threadIdx.x >> 6);
  const int lane = threadIdx.x & 63;
  const float4 v = *(const float4*)(Xin + (size_t)row * 256 + lane * 4);
  float y[4] = {v.x, v.y, v.z, v.w};

  float s = y[0] + y[1] + y[2] + y[3];
  #pragma unroll
  for (int m = 32; m >= 1; m >>= 1) s += __shfl_xor(s, m, 64);
  float mean = s * (1.0f / 256.0f);
  float sq = 0.f;
  #pragma unroll
  for (int i = 0; i < 4; ++i) { y[i] -= mean; sq += y[i] * y[i]; }
  #pragma unroll
  for (int m = 32; m >= 1; m >>= 1) sq += __shfl_xor(sq, m, 64);
  float rs = rsqrtf(sq * (1.0f / 256.0f) + 1e-6f);
  #pragma unroll
  for (int i = 0; i < 4; ++i) y[i] = y[i] * rs * g1[lane * 4 + i] + b1[lane * 4 + i];

  if (dbl) {
    float s2 = y[0] + y[1] + y[2] + y[3];
    #pragma unroll
    for (int m = 32; m >= 1; m >>= 1) s2 += __shfl_xor(s2, m, 64);
    float m2 = s2 * (1.0f / 256.0f);
    float sq2 = 0.f;
    #pragma unroll
    for (int i = 0; i < 4; ++i) { y[i] -= m2; sq2 += y[i] * y[i]; }
    #pragma unroll
    for (int m = 32; m >= 1; m >>= 1) sq2 += __shfl_xor(sq2, m, 64);
    float rs2 = rsqrtf(sq2 * (1.0f / 256.0f) + 1e-6f);
    #pragma unroll
    for (int i = 0; i < 4; ++i) y[i] = y[i] * rs2 * g2[lane * 4 + i] + b2[lane * 4 + i];
  }
  #pragma unroll
  for (int i = 0; i < 4; ++i) out[(size_t)row * 256 + lane * 4 + i] = f2bf(y[i]);
}

// ---------------- Q/K l2norm prepass (in place on qkv_bf) ----------------
// Q lanes (0..31) additionally scaled by SCALE*log2(e) so attention scores land
// directly in the exp2 domain.
__global__ __launch_bounds__(256) void qknorm_kernel(short* __restrict__ qkv) {
  const int row = blockIdx.x * 4 + (threadIdx.x >> 6);
  const int lane = threadIdx.x & 63;
  short* p = qkv + (size_t)row * 768 + lane * 8;
  short8 v = *(short8*)p;
  float f[8]; float ss = 0.f;
  #pragma unroll
  for (int j = 0; j < 8; ++j) { f[j] = bf2f(v[j]); ss += f[j] * f[j]; }
  ss += __shfl_xor(ss, 1, 64);
  ss += __shfl_xor(ss, 2, 64);
  float inv = 1.0f / fmaxf(sqrtf(ss), 1e-8f);
  const float C2 = 0.25503489702966368f;   // (1/sqrt(32)) * log2(e)
  float sc = (lane < 32) ? inv * C2 : inv;
  short8 o;
  #pragma unroll
  for (int j = 0; j < 8; ++j) o[j] = f2bf(f[j] * sc);
  *(short8*)p = o;
}

// ---------------- GEMM: C[M,N] = A[M,K] @ Bw[N,K]^T (+epilogue) ----------------
template<int BN, int EPI>
__global__ __launch_bounds__(256) void gemm_bt(
    const short* __restrict__ A, const short* __restrict__ Bw,
    const float* __restrict__ bias, float* __restrict__ X,
    short* __restrict__ Obf, const float* __restrict__ scale_p,
    int M, int N, int K)
{
  constexpr int MI = (BN == 128) ? 4 : 2;
  __shared__ __align__(16) short A_s[128 * 64];
  __shared__ __align__(16) short B_s[BN * 64];
  const int tid = threadIdx.x;
  const int lane = tid & 63;
  const int w = tid >> 6;
  const int lo4 = lane & 15, hi2 = lane >> 4;
  int wm, wn0;
  if (BN == 128) { wm = (w >> 1) * 64; wn0 = (w & 1) * 64; }
  else           { wm = w * 32;        wn0 = 0; }
  // bijective XCD swizzle (all grids divisible by 8)
  const int bid = blockIdx.x + blockIdx.y * gridDim.x;
  const int nwg = gridDim.x * gridDim.y;
  const int wg = (bid & 7) * (nwg >> 3) + (bid >> 3);
  const int tM = (wg / gridDim.x) * 128, tN = (wg % gridDim.x) * BN;

  f32x4 acc[MI][4];
  #pragma unroll
  for (int i = 0; i < MI; ++i)
    #pragma unroll
    for (int j = 0; j < 4; ++j) acc[i][j] = (f32x4){0.f, 0.f, 0.f, 0.f};

  const int swz = (lo4 & 7) << 3;

  for (int k0 = 0; k0 < K; k0 += 64) {
    #pragma unroll
    for (int ri = 0; ri < 4; ++ri) {
      int o = ri * 2048 + tid * 8;
      int row = o >> 6;
      int col = (o & 63) ^ ((row & 7) << 3);
      gload_lds16(&A_s[ri * 2048 + w * 512], A + (size_t)(tM + row) * K + k0 + col);
    }
    #pragma unroll
    for (int ri = 0; ri < BN / 32; ++ri) {
      int o = ri * 2048 + tid * 8;
      int row = o >> 6;
      int col = (o & 63) ^ ((row & 7) << 3);
      gload_lds16(&B_s[ri * 2048 + w * 512], Bw + (size_t)(tN + row) * K + k0 + col);
    }
    __syncthreads();
    #pragma unroll
    for (int kc = 0; kc < 2; ++kc) {
      short8 af[MI], bfr[4];
      #pragma unroll
      for (int i = 0; i < MI; ++i)
        af[i] = *(const short8*)&A_s[(wm + i * 16 + lo4) * 64 + ((kc * 32 + hi2 * 8) ^ swz)];
      #pragma unroll
      for (int j = 0; j < 4; ++j)
        bfr[j] = *(const short8*)&B_s[(wn0 + j * 16 + lo4) * 64 + ((kc * 32 + hi2 * 8) ^ swz)];
      #pragma unroll
      for (int i = 0; i < MI; ++i)
        #pragma unroll
        for (int j = 0; j < 4; ++j)
          acc[i][j] = mfma16(af[i], bfr[j], acc[i][j]);
    }
    __syncthreads();
  }

  float ts = 0.f;
  if (EPI == 1 || EPI == 3) ts = tanhf(scale_p[0]);

  #pragma unroll
  for (int i = 0; i < MI; ++i) {
    #pragma unroll
    for (int j = 0; j < 4; ++j) {
      #pragma unroll
      for (int r = 0; r < 4; ++r) {
        int row = tM + wm + i * 16 + hi2 * 4 + r;
        int col = tN + wn0 + j * 16 + lo4;
        float v = acc[i][j][r] + bias[col];
        size_t idx = (size_t)row * N + col;
        if (EPI == 0) {
          Obf[idx] = f2bf(v);
        } else if (EPI == 1) {
          X[idx] += ts * (v * 0.5f);
        } else if (EPI == 2) {
          float gl = 0.5f * v * (1.0f + erff(v * 0.70710678118f));
          Obf[idx] = f2bf(gl);
        } else {
          float o = X[idx] + ts * v;
          o = fminf(100.f, fmaxf(-100.f, o));
          X[idx] = o;
        }
      }
    }
  }
}

// ---------------- 64x64-tile GEMM for the N=256 layers ----------------
template<int EPI>
__global__ __launch_bounds__(256) void gemm64(
    const short* __restrict__ A, const short* __restrict__ Bw,
    const float* __restrict__ bias, float* __restrict__ X,
    const float* __restrict__ scale_p, int M, int N, int K)
{
  __shared__ __align__(16) short A_s[64 * 64];
  __shared__ __align__(16) short B_s[64 * 64];
  const int tid = threadIdx.x;
  const int lane = tid & 63;
  const int w = tid >> 6;
  const int lo4 = lane & 15, hi2 = lane >> 4;
  const int wm = (w >> 1) * 32, wn0 = (w & 1) * 32;
  const int bid = blockIdx.x + blockIdx.y * gridDim.x;
  const int nwg = gridDim.x * gridDim.y;
  const int wg = (bid & 7) * (nwg >> 3) + (bid >> 3);
  const int tM = (wg / gridDim.x) * 64, tN = (wg % gridDim.x) * 64;

  f32x4 acc[2][2];
  #pragma unroll
  for (int i = 0; i < 2; ++i)
    #pragma unroll
    for (int j = 0; j < 2; ++j) acc[i][j] = (f32x4){0.f, 0.f, 0.f, 0.f};

  const int swz = (lo4 & 7) << 3;

  for (int k0 = 0; k0 < K; k0 += 64) {
    #pragma unroll
    for (int ri = 0; ri < 2; ++ri) {
      int o = ri * 2048 + tid * 8;
      int row = o >> 6;
      int col = (o & 63) ^ ((row & 7) << 3);
      gload_lds16(&A_s[ri * 2048 + w * 512], A + (size_t)(tM + row) * K + k0 + col);
      gload_lds16(&B_s[ri * 2048 + w * 512], Bw + (size_t)(tN + row) * K + k0 + col);
    }
    __syncthreads();
    #pragma unroll
    for (int kc = 0; kc < 2; ++kc) {
      short8 af[2], bfr[2];
      #pragma unroll
      for (int i = 0; i < 2; ++i)
        af[i] = *(const short8*)&A_s[(wm + i * 16 + lo4) * 64 + ((kc * 32 + hi2 * 8) ^ swz)];
      #pragma unroll
      for (int j = 0; j < 2; ++j)
        bfr[j] = *(const short8*)&B_s[(wn0 + j * 16 + lo4) * 64 + ((kc * 32 + hi2 * 8) ^ swz)];
      #pragma unroll
      for (int i = 0; i < 2; ++i)
        #pragma unroll
        for (int j = 0; j < 2; ++j)
          acc[i][j] = mfma16(af[i], bfr[j], acc[i][j]);
    }
    __syncthreads();
  }

  float ts = tanhf(scale_p[0]);

  #pragma unroll
  for (int i = 0; i < 2; ++i) {
    #pragma unroll
    for (int j = 0; j < 2; ++j) {
      #pragma unroll
      for (int r = 0; r < 4; ++r) {
        int row = tM + wm + i * 16 + hi2 * 4 + r;
        int col = tN + wn0 + j * 16 + lo4;
        float v = acc[i][j][r] + bias[col];
        size_t idx = (size_t)row * N + col;
        if (EPI == 1) {
          X[idx] += ts * (v * 0.5f);
        } else {
          float o = X[idx] + ts * v;
          o = fminf(100.f, fmaxf(-100.f, o));
          X[idx] = o;
        }
      }
    }
  }
}

// ---------------- fused causal attention: barrier-free, LDS-free ----------------
// 512 blocks x 4 waves; each wave independently owns 32 queries (tile j = w*8+bj).
// K and V read directly from global (L2-resident per batch; b = bid&7 -> XCD-local).
// Q pre-scaled by SCALE*log2e -> numerator = v_exp(med3(S, +-14.43)).
#define KG_BODY_G(KG, PKO, MASKED)                                                 \
  {                                                                                \
    const short* kp = Kbase + (size_t)(t * 64 + (KG) * 32 + lo5) * 768;            \
    short8 kf0 = *(const short8*)(kp + hi1 * 8);                                   \
    short8 kf1 = *(const short8*)(kp + 16 + hi1 * 8);                              \
    f32x16 z = (f32x16)0.0f;                                                       \
    z = mfma32(kf0, qb[0], z);                                                     \
    z = mfma32(kf1, qb[1], z);                                                     \
    float pr[16];                                                                  \
    _Pragma("unroll")                                                              \
    for (int r = 0; r < 16; ++r) {                                                 \
      float sv = __builtin_amdgcn_fmed3f(z[r], -14.4269504f, 14.4269504f);         \
      float pe;                                                                    \
      asm("v_exp_f32 %0, %1" : "=v"(pe) : "v"(sv));                                \
      const int keyrel = (r & 3) + 8 * (r >> 2) + 4 * hi1;                         \
      if (MASKED) pe = (keyrel > lo5) ? 0.f : pe;                                  \
      if (pm) pe = ((pm >> ((KG) * 32 + keyrel)) & 1ull) ? 0.f : pe;               \
      pr[r] = pe;                                                                  \
      rsum += pe;                                                                  \
    }                                                                              \
    _Pragma("unroll")                                                              \
    for (int i = 0; i < 8; ++i) PKO[i] = cvtpk(pr[2 * i], pr[2 * i + 1]);          \
  }

#define PV_CHUNK_G(K2, PKO)                                                        \
  {                                                                                \
    const int half = (K2) & 1;                                                     \
    unsigned int keep0 = hi1 ? PKO[4 * half + 2] : PKO[4 * half + 0];              \
    unsigned int keep1 = hi1 ? PKO[4 * half + 3] : PKO[4 * half + 1];              \
    unsigned int send0 = hi1 ? PKO[4 * half + 0] : PKO[4 * half + 2];              \
    unsigned int send1 = hi1 ? PKO[4 * half + 1] : PKO[4 * half + 3];              \
    unsigned int r0 = (unsigned int)__shfl_xor((int)send0, 32, 64);                \
    unsigned int r1 = (unsigned int)__shfl_xor((int)send1, 32, 64);                \
    union { unsigned int u[4]; short8 s; } fa;                                     \
    fa.u[0] = hi1 ? r0 : keep0;                                                    \
    fa.u[1] = hi1 ? r1 : keep1;                                                    \
    fa.u[2] = hi1 ? keep0 : r0;                                                    \
    fa.u[3] = hi1 ? keep1 : r1;                                                    \
    short8 vb;                                                                     \
    _Pragma("unroll")                                                              \
    for (int jj = 0; jj < 8; ++jj)                                                 \
      vb[jj] = Vbase[(size_t)(t * 64 + (K2) * 16 + hi1 * 8 + jj) * 768 + lo5];     \
    if ((K2) & 1) oaccB = mfma32(fa.s, vb, oaccB);                                 \
    else          oaccA = mfma32(fa.s, vb, oaccA);                                 \
  }

__global__ __launch_bounds__(256) void attn_kernel(
    const short* __restrict__ qkv, const unsigned char* __restrict__ pad,
    short* __restrict__ ao)
{
  const int tid = threadIdx.x, lane = tid & 63, w = tid >> 6;
  const int lo5 = lane & 31, hi1 = lane >> 5;
  const int bid = blockIdx.x;            // 512
  const int b = bid & 7;                 // XCD-local batch
  const int h = (bid >> 3) & 7;
  const int bj = bid >> 6;               // 0..7
  const int j = w * 8 + bj;              // q-tile 0..31 (mixed cost within block)
  const size_t rowbase = (size_t)b * TT;
  const int qrow = j * 32 + lo5;
  const int ntile = (j >> 1) + 1;

  const short* Kbase = qkv + rowbase * 768 + 256 + h * 32;
  const short* Vbase = qkv + rowbase * 768 + 512 + h * 32;

  short8 qb[2];
  #pragma unroll
  for (int c2 = 0; c2 < 2; ++c2)
    qb[c2] = *(const short8*)(qkv + (rowbase + qrow) * 768 + h * 32 + c2 * 16 + hi1 * 8);

  f32x16 oaccA = (f32x16)0.0f;
  f32x16 oaccB = (f32x16)0.0f;
  float rsum = 0.f;

  int t = 0;
  #pragma unroll 2
  for (; t < ntile - 1; ++t) {
    const unsigned long long pm = __ballot(pad[rowbase + t * 64 + lane] != 0);
    unsigned int pk0[8], pk1[8];
    KG_BODY_G(0, pk0, false)
    PV_CHUNK_G(0, pk0)
    PV_CHUNK_G(1, pk0)
    KG_BODY_G(1, pk1, false)
    PV_CHUNK_G(2, pk1)
    PV_CHUNK_G(3, pk1)
  }
  {  // final (diagonal) tile: j even -> kg0 masked only; j odd -> kg0 full + kg1 masked
    const unsigned long long pm = __ballot(pad[rowbase + t * 64 + lane] != 0);
    unsigned int pk0[8], pk1[8];
    if (j & 1) {
      KG_BODY_G(0, pk0, false)
      PV_CHUNK_G(0, pk0)
      PV_CHUNK_G(1, pk0)
      KG_BODY_G(1, pk1, true)
      PV_CHUNK_G(2, pk1)
      PV_CHUNK_G(3, pk1)
    } else {
      KG_BODY_G(0, pk0, true)
      PV_CHUNK_G(0, pk0)
      PV_CHUNK_G(1, pk0)
    }
  }

  rsum += __shfl_xor(rsum, 32, 64);
  float rinv = 1.0f / fmaxf(rsum, 1e-30f);
  #pragma unroll
  for (int r = 0; r < 16; ++r) {
    int ql = (r & 3) + 8 * (r >> 2) + 4 * hi1;
    float riv = __shfl(rinv, ql, 64);
    int qg = j * 32 + ql;
    ao[(rowbase + qg) * 256 + h * 32 + lo5] = f2bf((oaccA[r] + oaccB[r]) * riv);
  }
}

extern "C" void kernel_launch(void* const* d_in, const int* in_sizes, int n_in,
                              void* d_out, int out_size, void* d_ws, size_t ws_size,
                              hipStream_t stream) {
  const float* x_in  = (const float*)d_in[0];
  const unsigned char* pad = (const unsigned char*)d_in[1];
  const float* ln1_g = (const float*)d_in[2];
  const float* ln1_b = (const float*)d_in[3];
  const float* qn_g  = (const float*)d_in[4];
  const float* qn_b  = (const float*)d_in[5];
  const float* Wqkv  = (const float*)d_in[6];
  const float* bqkv  = (const float*)d_in[7];
  const float* Wo    = (const float*)d_in[8];
  const float* bo    = (const float*)d_in[9];
  const float* ln2_g = (const float*)d_in[10];
  const float* ln2_b = (const float*)d_in[11];
  const float* W1    = (const float*)d_in[12];
  const float* b1    = (const float*)d_in[13];
  const float* W2    = (const float*)d_in[14];
  const float* b2    = (const float*)d_in[15];
  const float* alpha = (const float*)d_in[16];
  const float* beta  = (const float*)d_in[17];

  char* ws = (char*)d_ws;
  size_t off = 0;
  short* wqkv_bf = (short*)(ws + off); off += (size_t)4 * 768 * 256 * 2;
  short* wo_bf   = (short*)(ws + off); off += (size_t)4 * 256 * 256 * 2;
  short* w1_bf   = (short*)(ws + off); off += (size_t)4 * 1024 * 256 * 2;
  short* w2_bf   = (short*)(ws + off); off += (size_t)4 * 256 * 1024 * 2;
  short* h_bf    = (short*)(ws + off); off += (size_t)BT * 256 * 2;
  short* qkv_bf  = (short*)(ws + off); off += (size_t)BT * 768 * 2;
  short* ao_bf   = (short*)(ws + off); off += (size_t)BT * 256 * 2;
  short* g_bf    = (short*)(ws + off); off += (size_t)BT * 1024 * 2;

  float* X = (float*)d_out;

  hipMemcpyAsync(d_out, x_in, (size_t)BT * DD * 4, hipMemcpyDeviceToDevice, stream);
  cvt_kernel<<<768,  256, 0, stream>>>((const float4*)Wqkv, (short4v*)wqkv_bf, 4 * 768 * 256 / 4);
  cvt_kernel<<<256,  256, 0, stream>>>((const float4*)Wo,   (short4v*)wo_bf,   4 * 256 * 256 / 4);
  cvt_kernel<<<1024, 256, 0, stream>>>((const float4*)W1,   (short4v*)w1_bf,   4 * 1024 * 256 / 4);
  cvt_kernel<<<1024, 256, 0, stream>>>((const float4*)W2,   (short4v*)w2_bf,   4 * 256 * 1024 / 4);

  for (int l = 0; l < 4; ++l) {
    ln_kernel<<<2048, 256, 0, stream>>>(X, ln1_g + l * 256, ln1_b + l * 256,
                                        qn_g + l * 256, qn_b + l * 256, h_bf, 1);
    gemm_bt<128, 0><<<dim3(6, 64), 256, 0, stream>>>(h_bf, wqkv_bf + (size_t)l * 768 * 256,
                                                     bqkv + l * 768, nullptr, qkv_bf, nullptr,
                                                     8192, 768, 256);
    qknorm_kernel<<<2048, 256, 0, stream>>>(qkv_bf);
    attn_kernel<<<512, 256, 0, stream>>>(qkv_bf, pad, ao_bf);
    gemm64<1><<<dim3(4, 128), 256, 0, stream>>>(ao_bf, wo_bf + (size_t)l * 256 * 256,
                                                bo + l * 256, X, alpha + l,
                                                8192, 256, 256);
    ln_kernel<<<2048, 256, 0, stream>>>(X, ln2_g + l * 256, ln2_b + l * 256,
                                        nullptr, nullptr, h_bf, 0);
    gemm_bt<128, 2><<<dim3(8, 64), 256, 0, stream>>>(h_bf, w1_bf + (size_t)l * 1024 * 256,
                                                     b1 + l * 1024, nullptr, g_bf, nullptr,
                                                     8192, 1024, 256);
    gemm64<3><<<dim3(4, 128), 256, 0, stream>>>(g_bf, w2_bf + (size_t)l * 256 * 1024,
                                                b2 + l * 256, X, beta + l,
                                                8192, 256, 1024);
  }
}